// Round 2
// baseline (160.633 us; speedup 1.0000x reference)
//
#include <hip/hip_runtime.h>
#include <math.h>

// Maxwell IIR scan. stress[t] = a*stress[t-1] + E*(s[t]-s[t-1]), a=exp(-dt*E/eta),
// stress[0] = E*s[0] + eta*r[0].
//
// Reformulation: y[t]=stress[t]-E*s[t] => y[t]=a*y[t-1]+c*s[t-1], c=E*(a-1),
// so  stress[t] = E*s[t] + c*Z[t-1] + a^t*eta*r0,  Z = plain scan of s
// (Z[k]=a*Z[k-1]+s[k]). No differencing, no neighbor shuffle needed.
//
// R3: DS-bpermute scan chains = latency wall (45us, VALU 11%, HBM 35%).
// R4: 32 contig elem/lane broke per-instruction coalescing (64 lines/load) -> 52us.
// R5: coalesced float4/lane layout + DPP row-scan + readlane combine: 41.1us.
// R7: counters showed kernel HBM-traffic-bound in timed iters (L3 thrashed by
//     harness 268MB fills; profiled FETCH=36MB is warm-L3 artifact). Warm-up
//     re-reads were 31MB of 162MB traffic. Now each wave owns a SPAN of 4
//     consecutive chunks, carrying S exactly across them -> warm-up only at
//     span starts (7MB), plus prefetch-next-chunk software pipeline.
//     Traffic 162->139MB; predict 41 -> ~34us.

#define DT_F  0.1f
#define S_LEN 65536
#define B_ROWS 256
#define CHUNK 2048
#define WARM  1024
#define KCH   4                       // chunks per span (per wave)
#define SPAN  (CHUNK * KCH)           // 8192
#define SPR   (S_LEN / SPAN)          // 8 spans per row

typedef float nfloat4 __attribute__((ext_vector_type(4)));

template<int N>
__device__ __forceinline__ float dpp_shr(float x) {
    // lane l receives lane l-N within its 16-lane row; out-of-row lanes get 0.
    return __int_as_float(__builtin_amdgcn_update_dpp(
        0, __float_as_int(x), 0x110 + N, 0xF, 0xF, false));
}
__device__ __forceinline__ float rdl(float x, int l) {
    return __int_as_float(__builtin_amdgcn_readlane(__float_as_int(x), l));
}

struct G8 { nfloat4 g0, g1, g2, g3, g4, g5, g6, g7; };

__global__ __launch_bounds__(256) void maxwell_scan(
    const float* __restrict__ strain,
    const float* __restrict__ rate,
    const float* __restrict__ log_E,
    const float* __restrict__ log_eta,
    float* __restrict__ out)
{
    const int lane = threadIdx.x & 63;
    const int wid  = blockIdx.x * 4 + (threadIdx.x >> 6);  // 0..2047
    const int row  = wid / SPR;
    const int sp   = wid % SPR;

    const float E   = __expf(log_E[0]);
    const float eta = __expf(log_eta[0]);
    const float lam = -DT_F * E / eta;          // ln(a)
    const float a   = __expf(lam);
    const float a2 = a * a, a3 = a2 * a, a4 = a2 * a2, a8 = a4 * a4;
    const float a16 = a8 * a8, a32 = a16 * a16, a64 = a32 * a32;
    const float a128 = a64 * a64, a256 = a128 * a128;
    const float cc = E * (a - 1.0f);
    const float cca1 = cc * a, cca2 = cc * a2, cca3 = cc * a3;

    const int  lrow = lane & 15;
    const float alane = __expf(lam * (float)(4 * lane));   // a^(4*lane)
    const float wX    = __expf(lam * (float)(4 * lrow));   // a^(4*lrow)
    const bool row0 = (lrow == 0);
    const bool ge16 = lane >= 16, ge32 = lane >= 32, ge48 = lane >= 48;

    const int rowbase = row * S_LEN;
    const int t0 = sp * SPAN;
    const nfloat4* s4 = (const nfloat4*)(strain + rowbase);
    nfloat4*       o4 = (nfloat4*)(out + rowbase);
    const int vbase = (t0 >> 2) + lane;         // chunk k group g at vbase + k*512 + g*64

    // ---- issue warm-up loads FIRST (consumed first; vmcnt FIFO keeps
    //      chunk-0 loads in flight during warm-up compute) ----
    nfloat4 w0, w1, w2, w3;
    if (sp != 0) {
        const int vw = ((t0 - WARM) >> 2) + lane;
        w0 = s4[vw]; w1 = s4[vw + 64]; w2 = s4[vw + 128]; w3 = s4[vw + 192];
    }
    // ---- chunk 0 loads ----
    G8 cur;
    cur.g0 = s4[vbase +   0]; cur.g1 = s4[vbase +  64];
    cur.g2 = s4[vbase + 128]; cur.g3 = s4[vbase + 192];
    cur.g4 = s4[vbase + 256]; cur.g5 = s4[vbase + 320];
    cur.g6 = s4[vbase + 384]; cur.g7 = s4[vbase + 448];

    float etar0 = 0.0f;
    if (sp == 0) etar0 = eta * rate[rowbase];    // only row-start spans

    float S = 0.0f;   // Z-scan state entering next group

    if (sp != 0) {
        auto warmg = [&](nfloat4 wf) {
            float fl = wf.x;
            fl = fmaf(a, fl, wf.y); fl = fmaf(a, fl, wf.z); fl = fmaf(a, fl, wf.w);
            float D = fl, v;
            v = dpp_shr<1>(D); D = fmaf(a4,  v, D);
            v = dpp_shr<2>(D); D = fmaf(a8,  v, D);
            v = dpp_shr<4>(D); D = fmaf(a16, v, D);
            v = dpp_shr<8>(D); D = fmaf(a32, v, D);
            float r15 = rdl(D, 15), r31 = rdl(D, 31), r47 = rdl(D, 47), r63 = rdl(D, 63);
            float P1 = r15;
            float P2 = fmaf(a64, P1, r31);
            float P3 = fmaf(a64, P2, r47);
            float T  = fmaf(a64, P3, r63);       // group total (256 elems)
            S = fmaf(a256, S, T);
        };
        warmg(w0); warmg(w1); warmg(w2); warmg(w3);
    }

    const float rl0 = etar0 * alane;             // eta*r0 * a^(4*lane)
    const float rl1 = rl0 * a, rl2 = rl0 * a2, rl3 = rl0 * a3;
    float base = 1.0f;                           // a^(256*g) for r0 term

    auto payg = [&](nfloat4 pf, int vo) {
        // intra-lane inclusive scan of strain (Z-scan, zero init)
        float fl0 = pf.x;
        float fl1 = fmaf(a, fl0, pf.y);
        float fl2 = fmaf(a, fl1, pf.z);
        float fl3 = fmaf(a, fl2, pf.w);
        // cross-lane weighted scan of lane totals
        float D = fl3, v;
        v = dpp_shr<1>(D); D = fmaf(a4,  v, D);
        v = dpp_shr<2>(D); D = fmaf(a8,  v, D);
        v = dpp_shr<4>(D); D = fmaf(a16, v, D);
        v = dpp_shr<8>(D); D = fmaf(a32, v, D);
        float r15 = rdl(D, 15), r31 = rdl(D, 31), r47 = rdl(D, 47), r63 = rdl(D, 63);
        float P1 = r15;
        float P2 = fmaf(a64, P1, r31);
        float P3 = fmaf(a64, P2, r47);
        float T  = fmaf(a64, P3, r63);
        // row-prefix for this lane's row (rows of 16 lanes)
        float Pv = ge48 ? P3 : (ge32 ? P2 : (ge16 ? P1 : 0.0f));
        // Z (group-local) at this lane's position-1: D_{lane-1}^final
        float Xd = dpp_shr<1>(D);                     // local scan of lane-1
        float X  = row0 ? Pv : fmaf(wX, Pv, Xd);
        float Xs = fmaf(alane, S, X);                 // + incoming state
        // stress[t] = E*s[t] + c*Z[t-1] + a^t*eta*r0
        nfloat4 o;
        o.x = fmaf(cc,   Xs, E * pf.x);
        o.y = fmaf(cca1, Xs, fmaf(cc, fl0, E * pf.y));
        o.z = fmaf(cca2, Xs, fmaf(cc, fl1, E * pf.z));
        o.w = fmaf(cca3, Xs, fmaf(cc, fl2, E * pf.w));
        o.x = fmaf(base, rl0, o.x);
        o.y = fmaf(base, rl1, o.y);
        o.z = fmaf(base, rl2, o.z);
        o.w = fmaf(base, rl3, o.w);
        o4[vo] = o;
        S = fmaf(a256, S, T);
        base *= a256;
    };

    #pragma unroll
    for (int k = 0; k < KCH; ++k) {
        G8 nxt;
        if (k + 1 < KCH) {
            const int vn = vbase + (k + 1) * 512;
            nxt.g0 = s4[vn +   0]; nxt.g1 = s4[vn +  64];
            nxt.g2 = s4[vn + 128]; nxt.g3 = s4[vn + 192];
            nxt.g4 = s4[vn + 256]; nxt.g5 = s4[vn + 320];
            nxt.g6 = s4[vn + 384]; nxt.g7 = s4[vn + 448];
        }
        const int vo = vbase + k * 512;
        payg(cur.g0, vo +   0); payg(cur.g1, vo +  64);
        payg(cur.g2, vo + 128); payg(cur.g3, vo + 192);
        payg(cur.g4, vo + 256); payg(cur.g5, vo + 320);
        payg(cur.g6, vo + 384); payg(cur.g7, vo + 448);
        if (k + 1 < KCH) cur = nxt;
    }
}

extern "C" void kernel_launch(void* const* d_in, const int* in_sizes, int n_in,
                              void* d_out, int out_size, void* d_ws, size_t ws_size,
                              hipStream_t stream) {
    const float* strain  = (const float*)d_in[0];
    const float* rate    = (const float*)d_in[1];
    const float* log_E   = (const float*)d_in[2];
    const float* log_eta = (const float*)d_in[3];
    float* out = (float*)d_out;

    const int total_spans = B_ROWS * SPR;       // 2048 waves
    const int blocks = total_spans / 4;         // 4 waves / 256-thread block = 512
    maxwell_scan<<<blocks, 256, 0, stream>>>(strain, rate, log_E, log_eta, out);
}

// Round 3
// 159.159 us; speedup vs baseline: 1.0093x; 1.0093x over previous
//
#include <hip/hip_runtime.h>
#include <math.h>

// Maxwell IIR scan. stress[t] = a*stress[t-1] + E*(s[t]-s[t-1]), a=exp(-dt*E/eta),
// stress[0] = E*s[0] + eta*r[0].
//
// Reformulation: y[t]=stress[t]-E*s[t] => y[t]=a*y[t-1]+c*s[t-1], c=E*(a-1),
// so  stress[t] = E*s[t] + c*Z[t-1] + a^t*eta*r0,  Z = plain scan of s
// (Z[k]=a*Z[k-1]+s[k]). No differencing, no neighbor shuffle needed.
//
// R3: DS-bpermute scan chains = latency wall (45us, VALU 11%, HBM 35%).
// R4: 32 contig elem/lane broke per-instruction coalescing (64 lines/load) -> 52us.
// R5: coalesced float4/lane layout + DPP row-scan + readlane ladder: 41.1us.
// R7: span-of-4-chunks/wave cut waves 8192->2048: REGRESSED to 50us
//     (Occupancy 31->20%, VALUBusy 13->9%, FETCH identical 36.4MB).
//     Lesson: kernel is LATENCY-bound; warm-up reads were L3-hits anyway.
// R8: (a) revert to 8192 waves (32/CU, proven by R7's inverse A/B);
//     (b) replace 4x readlane + fmaf-ladder + select with row_bcast15/31
//         DPP combine (per-lane weights) + wave_shr1 for the exclusive
//         value -> full-wave weighted scan, 1 readlane/group, no SALU
//         round-trip on the critical path;
//     (c) WARM 1024->512 (a^512~6e-3, stress err ~2e-3 << 0.0156 tol).
//     Predict 34-37us profiled.

#define DT_F  0.1f
#define S_LEN 65536
#define B_ROWS 256
#define CHUNK 2048
#define WARM  512
#define CPR   (S_LEN / CHUNK)   // 32 chunks per row

typedef float nfloat4 __attribute__((ext_vector_type(4)));

template<int CTRL, int RM>
__device__ __forceinline__ float dpp0(float x) {
    // DPP with old=0: lanes with no valid source (or masked rows) get 0.
    return __int_as_float(__builtin_amdgcn_update_dpp(
        0, __float_as_int(x), CTRL, RM, 0xF, false));
}
template<int N>
__device__ __forceinline__ float dpp_shr(float x) { return dpp0<0x110 + N, 0xF>(x); }
__device__ __forceinline__ float bcast15(float x) { return dpp0<0x142, 0xA>(x); } // lane15->row1, lane47->row3
__device__ __forceinline__ float bcast31(float x) { return dpp0<0x143, 0xC>(x); } // lane31->rows2,3
__device__ __forceinline__ float wshr1(float x)   { return dpp0<0x138, 0xF>(x); } // whole-wave shift, lane0->0
__device__ __forceinline__ float rdl(float x, int l) {
    return __int_as_float(__builtin_amdgcn_readlane(__float_as_int(x), l));
}

__global__ __launch_bounds__(256) void maxwell_scan(
    const float* __restrict__ strain,
    const float* __restrict__ rate,
    const float* __restrict__ log_E,
    const float* __restrict__ log_eta,
    float* __restrict__ out)
{
    const int lane = threadIdx.x & 63;
    const int wid  = blockIdx.x * 4 + (threadIdx.x >> 6);  // 0..8191
    const int row  = wid / CPR;
    const int c    = wid % CPR;

    const float E   = __expf(log_E[0]);
    const float eta = __expf(log_eta[0]);
    const float lam = -DT_F * E / eta;          // ln(a)
    const float a   = __expf(lam);
    const float a2 = a * a, a3 = a2 * a, a4 = a2 * a2, a8 = a4 * a4;
    const float a16 = a8 * a8, a32 = a16 * a16, a64 = a32 * a32;
    const float a128 = a64 * a64, a256 = a128 * a128;
    const float cc = E * (a - 1.0f);
    const float cca1 = cc * a, cca2 = cc * a2, cca3 = cc * a3;

    const int  lrow = lane & 15;
    const float alane = __expf(lam * (float)(4 * lane));   // a^(4*lane)
    const float wX    = __expf(lam * (float)(4 * lrow));   // a^(4*lrow)
    const float wm1   = wX * a4;                           // a^(4*(lrow+1))
    const float wm2   = (lane >= 48) ? wm1 * a64 : wm1;    // row3 jumps over rows 0-1

    const int rowbase = row * S_LEN;
    const int t0 = c * CHUNK;
    const nfloat4* s4 = (const nfloat4*)(strain + rowbase);
    nfloat4*       o4 = (nfloat4*)(out + rowbase);

    // ---- warm-up loads first (consumed first), then payload; all coalesced ----
    nfloat4 w0, w1;
    if (c != 0) {
        const int vw = ((t0 - WARM) >> 2) + lane;
        w0 = s4[vw]; w1 = s4[vw + 64];
    }
    const int vp = (t0 >> 2) + lane;            // payload group g at vp + 64*g
    nfloat4 p0 = s4[vp +   0], p1 = s4[vp +  64], p2 = s4[vp + 128], p3 = s4[vp + 192];
    nfloat4 p4 = s4[vp + 256], p5 = s4[vp + 320], p6 = s4[vp + 384], p7 = s4[vp + 448];

    float S = 0.0f;   // Z-scan state entering next group

    // full-wave weighted inclusive scan of lane totals (Kogge-Stone rows +
    // bcast combine); returns W in-place semantics via return value
    auto scanW = [&](float fl3) -> float {
        float D = fl3, v;
        v = dpp_shr<1>(D); D = fmaf(a4,  v, D);
        v = dpp_shr<2>(D); D = fmaf(a8,  v, D);
        v = dpp_shr<4>(D); D = fmaf(a16, v, D);
        v = dpp_shr<8>(D); D = fmaf(a32, v, D);
        v = bcast15(D);    D = fmaf(wm1, v, D);   // rows 1,3 += w*(prev row total)
        v = bcast31(D);    D = fmaf(wm2, v, D);   // rows 2,3 += w*(prefix of rows 0-1)
        return D;
    };

    if (c != 0) {
        auto warmg = [&](nfloat4 wf) {
            float fl = wf.x;
            fl = fmaf(a, fl, wf.y); fl = fmaf(a, fl, wf.z); fl = fmaf(a, fl, wf.w);
            float W = scanW(fl);
            float T = rdl(W, 63);                 // group total (256 elems)
            S = fmaf(a256, S, T);
        };
        warmg(w0); warmg(w1);
    }

    float etar0 = 0.0f;
    if (c == 0) etar0 = eta * rate[rowbase];     // only row-start chunks
    const float rl0 = etar0 * alane;             // eta*r0 * a^(4*lane)
    const float rl1 = rl0 * a, rl2 = rl0 * a2, rl3 = rl0 * a3;
    float base = 1.0f;                           // a^(256*g) for r0 term

    auto payg = [&](nfloat4 pf, int vo) {
        // intra-lane inclusive scan of strain (Z-scan, zero init)
        float fl0 = pf.x;
        float fl1 = fmaf(a, fl0, pf.y);
        float fl2 = fmaf(a, fl1, pf.z);
        float fl3 = fmaf(a, fl2, pf.w);
        float W = scanW(fl3);                    // full-wave weighted scan
        float T = rdl(W, 63);                    // chunk-group total
        float X = wshr1(W);                      // W[lane-1], lane0 -> 0
        float Xs = fmaf(alane, S, X);            // + incoming state
        // stress[t] = E*s[t] + c*Z[t-1] + a^t*eta*r0
        nfloat4 o;
        o.x = fmaf(cc,   Xs, E * pf.x);
        o.y = fmaf(cca1, Xs, fmaf(cc, fl0, E * pf.y));
        o.z = fmaf(cca2, Xs, fmaf(cc, fl1, E * pf.z));
        o.w = fmaf(cca3, Xs, fmaf(cc, fl2, E * pf.w));
        o.x = fmaf(base, rl0, o.x);
        o.y = fmaf(base, rl1, o.y);
        o.z = fmaf(base, rl2, o.z);
        o.w = fmaf(base, rl3, o.w);
        o4[vo] = o;
        S = fmaf(a256, S, T);
        base *= a256;
    };
    payg(p0, vp +   0); payg(p1, vp +  64); payg(p2, vp + 128); payg(p3, vp + 192);
    payg(p4, vp + 256); payg(p5, vp + 320); payg(p6, vp + 384); payg(p7, vp + 448);
}

extern "C" void kernel_launch(void* const* d_in, const int* in_sizes, int n_in,
                              void* d_out, int out_size, void* d_ws, size_t ws_size,
                              hipStream_t stream) {
    const float* strain  = (const float*)d_in[0];
    const float* rate    = (const float*)d_in[1];
    const float* log_E   = (const float*)d_in[2];
    const float* log_eta = (const float*)d_in[3];
    float* out = (float*)d_out;

    const int total_chunks = B_ROWS * CPR;      // 8192 waves
    const int blocks = total_chunks / 4;        // 4 waves / 256-thread block
    maxwell_scan<<<blocks, 256, 0, stream>>>(strain, rate, log_E, log_eta, out);
}

// Round 4
// 156.818 us; speedup vs baseline: 1.0243x; 1.0149x over previous
//
#include <hip/hip_runtime.h>
#include <math.h>

// Maxwell IIR scan. stress[t] = a*stress[t-1] + E*(s[t]-s[t-1]), a=exp(-dt*E/eta),
// stress[0] = E*s[0] + eta*r[0].
//
// Reformulation: y[t]=stress[t]-E*s[t] => y[t]=a*y[t-1]+c*s[t-1], c=E*(a-1),
// so  stress[t] = E*s[t] + c*Z[t-1] + a^t*eta*r0,  Z = plain scan of s
// (Z[k]=a*Z[k-1]+s[k]). No differencing, no neighbor shuffle needed.
//
// R3: DS-bpermute scan chains = latency wall (45us, VALU 11%, HBM 35%).
// R4: 32 contig elem/lane broke per-instruction coalescing -> 52us.
// R5: coalesced float4/lane + DPP row-scan + readlane ladder: 41.1us.
// R7: 4-chunk spans cut waves 8192->2048: REGRESSED 50us (occupancy 20%).
// R8: DPP bcast combine (no SALU round-trip) + WARM 512: 41.0us == R5.
//     Chain micro-opts don't move it; VALU 11%, HBM 31%, occupancy 39%.
//     Diagnosis: grid = exactly one residency generation (8192 waves);
//     avg wave lifetime ~16us inside a 41us kernel => staggered burst +
//     long drain with decaying MLP. No pipe is busy; it's a drain tail.
// R9: CHUNK 2048->1024: 16384 waves / 4096 blocks = TWO generations.
//     Retiring waves are backfilled -> sustained memory pressure through
//     the drain; per-wave serial chain halves. Cost: warm reads x2 (32MB
//     cold), harmless unless BW-bound. Predict 28-33us; if unchanged,
//     mixed-stream fabric ceiling -> nt stores next, else roofline.

#define DT_F  0.1f
#define S_LEN 65536
#define B_ROWS 256
#define CHUNK 1024
#define WARM  512
#define CPR   (S_LEN / CHUNK)   // 64 chunks per row

typedef float nfloat4 __attribute__((ext_vector_type(4)));

template<int CTRL, int RM>
__device__ __forceinline__ float dpp0(float x) {
    // DPP with old=0: lanes with no valid source (or masked rows) get 0.
    return __int_as_float(__builtin_amdgcn_update_dpp(
        0, __float_as_int(x), CTRL, RM, 0xF, false));
}
template<int N>
__device__ __forceinline__ float dpp_shr(float x) { return dpp0<0x110 + N, 0xF>(x); }
__device__ __forceinline__ float bcast15(float x) { return dpp0<0x142, 0xA>(x); } // lane15->row1, lane47->row3
__device__ __forceinline__ float bcast31(float x) { return dpp0<0x143, 0xC>(x); } // lane31->rows2,3
__device__ __forceinline__ float wshr1(float x)   { return dpp0<0x138, 0xF>(x); } // whole-wave shift, lane0->0
__device__ __forceinline__ float rdl(float x, int l) {
    return __int_as_float(__builtin_amdgcn_readlane(__float_as_int(x), l));
}

__global__ __launch_bounds__(256) void maxwell_scan(
    const float* __restrict__ strain,
    const float* __restrict__ rate,
    const float* __restrict__ log_E,
    const float* __restrict__ log_eta,
    float* __restrict__ out)
{
    const int lane = threadIdx.x & 63;
    const int wid  = blockIdx.x * 4 + (threadIdx.x >> 6);  // 0..16383
    const int row  = wid / CPR;
    const int c    = wid % CPR;

    const float E   = __expf(log_E[0]);
    const float eta = __expf(log_eta[0]);
    const float lam = -DT_F * E / eta;          // ln(a)
    const float a   = __expf(lam);
    const float a2 = a * a, a3 = a2 * a, a4 = a2 * a2, a8 = a4 * a4;
    const float a16 = a8 * a8, a32 = a16 * a16, a64 = a32 * a32;
    const float a128 = a64 * a64, a256 = a128 * a128;
    const float cc = E * (a - 1.0f);
    const float cca1 = cc * a, cca2 = cc * a2, cca3 = cc * a3;

    const int  lrow = lane & 15;
    const float alane = __expf(lam * (float)(4 * lane));   // a^(4*lane)
    const float wX    = __expf(lam * (float)(4 * lrow));   // a^(4*lrow)
    const float wm1   = wX * a4;                           // a^(4*(lrow+1))
    const float wm2   = (lane >= 48) ? wm1 * a64 : wm1;    // row3 jumps over rows 0-1

    const int rowbase = row * S_LEN;
    const int t0 = c * CHUNK;
    const nfloat4* s4 = (const nfloat4*)(strain + rowbase);
    nfloat4*       o4 = (nfloat4*)(out + rowbase);

    // ---- warm-up loads first (consumed first), then payload; all coalesced ----
    nfloat4 w0, w1;
    if (c != 0) {
        const int vw = ((t0 - WARM) >> 2) + lane;
        w0 = s4[vw]; w1 = s4[vw + 64];
    }
    const int vp = (t0 >> 2) + lane;            // payload group g at vp + 64*g
    nfloat4 p0 = s4[vp +   0], p1 = s4[vp +  64], p2 = s4[vp + 128], p3 = s4[vp + 192];

    float S = 0.0f;   // Z-scan state entering next group

    // full-wave weighted inclusive scan of lane totals (Kogge-Stone rows +
    // bcast combine)
    auto scanW = [&](float fl3) -> float {
        float D = fl3, v;
        v = dpp_shr<1>(D); D = fmaf(a4,  v, D);
        v = dpp_shr<2>(D); D = fmaf(a8,  v, D);
        v = dpp_shr<4>(D); D = fmaf(a16, v, D);
        v = dpp_shr<8>(D); D = fmaf(a32, v, D);
        v = bcast15(D);    D = fmaf(wm1, v, D);   // rows 1,3 += w*(prev row total)
        v = bcast31(D);    D = fmaf(wm2, v, D);   // rows 2,3 += w*(prefix of rows 0-1)
        return D;
    };

    if (c != 0) {
        auto warmg = [&](nfloat4 wf) {
            float fl = wf.x;
            fl = fmaf(a, fl, wf.y); fl = fmaf(a, fl, wf.z); fl = fmaf(a, fl, wf.w);
            float W = scanW(fl);
            float T = rdl(W, 63);                 // group total (256 elems)
            S = fmaf(a256, S, T);
        };
        warmg(w0); warmg(w1);
    }

    float etar0 = 0.0f;
    if (c == 0) etar0 = eta * rate[rowbase];     // only row-start chunks
    const float rl0 = etar0 * alane;             // eta*r0 * a^(4*lane)
    const float rl1 = rl0 * a, rl2 = rl0 * a2, rl3 = rl0 * a3;
    float base = 1.0f;                           // a^(256*g) for r0 term

    auto payg = [&](nfloat4 pf, int vo) {
        // intra-lane inclusive scan of strain (Z-scan, zero init)
        float fl0 = pf.x;
        float fl1 = fmaf(a, fl0, pf.y);
        float fl2 = fmaf(a, fl1, pf.z);
        float fl3 = fmaf(a, fl2, pf.w);
        float W = scanW(fl3);                    // full-wave weighted scan
        float T = rdl(W, 63);                    // chunk-group total
        float X = wshr1(W);                      // W[lane-1], lane0 -> 0
        float Xs = fmaf(alane, S, X);            // + incoming state
        // stress[t] = E*s[t] + c*Z[t-1] + a^t*eta*r0
        nfloat4 o;
        o.x = fmaf(cc,   Xs, E * pf.x);
        o.y = fmaf(cca1, Xs, fmaf(cc, fl0, E * pf.y));
        o.z = fmaf(cca2, Xs, fmaf(cc, fl1, E * pf.z));
        o.w = fmaf(cca3, Xs, fmaf(cc, fl2, E * pf.w));
        o.x = fmaf(base, rl0, o.x);
        o.y = fmaf(base, rl1, o.y);
        o.z = fmaf(base, rl2, o.z);
        o.w = fmaf(base, rl3, o.w);
        o4[vo] = o;
        S = fmaf(a256, S, T);
        base *= a256;
    };
    payg(p0, vp +   0); payg(p1, vp +  64); payg(p2, vp + 128); payg(p3, vp + 192);
}

extern "C" void kernel_launch(void* const* d_in, const int* in_sizes, int n_in,
                              void* d_out, int out_size, void* d_ws, size_t ws_size,
                              hipStream_t stream) {
    const float* strain  = (const float*)d_in[0];
    const float* rate    = (const float*)d_in[1];
    const float* log_E   = (const float*)d_in[2];
    const float* log_eta = (const float*)d_in[3];
    float* out = (float*)d_out;

    const int total_chunks = B_ROWS * CPR;      // 16384 waves
    const int blocks = total_chunks / 4;        // 4 waves / 256-thread block = 4096
    maxwell_scan<<<blocks, 256, 0, stream>>>(strain, rate, log_E, log_eta, out);
}

// Round 5
// 156.204 us; speedup vs baseline: 1.0284x; 1.0039x over previous
//
#include <hip/hip_runtime.h>
#include <math.h>

// Maxwell IIR scan. stress[t] = a*stress[t-1] + E*(s[t]-s[t-1]), a=exp(-dt*E/eta),
// stress[0] = E*s[0] + eta*r[0].
//
// Reformulation: y[t]=stress[t]-E*s[t] => y[t]=a*y[t-1]+c*s[t-1], c=E*(a-1),
// so  stress[t] = E*s[t] + c*Z[t-1] + a^t*eta*r0,  Z = plain scan of s
// (Z[k]=a*Z[k-1]+s[k]). No differencing, no neighbor shuffle needed.
//
// R3: DS-bpermute scan chains = latency wall (45us).
// R4: 32 contig elem/lane broke coalescing -> 52us.
// R5: coalesced float4/lane + DPP row-scan + readlane ladder: 41.1us.
// R7: 4-chunk SERIAL spans cut waves to 2048: REGRESSED 50us (occupancy 20%).
// R8: DPP bcast combine + WARM 512: 41.0us == R5 (chain not the gate).
// R9: CHUNK 1024, 16384 waves (2 residency generations): ~38.5us.
//     Timed-region model: ~160MB HBM (L3 thrashed by harness fills) at
//     ~5TB/s == ~80% of copy ceiling -> nearly traffic-bound; the 32MB of
//     warm-up re-reads (20% of traffic) is the remaining overhead.
// R10: intra-block LDS handoff. 4 waves/block own 4 CONSECUTIVE chunks.
//     Phase1: each wave scans its 4 groups (W_g); lane63 stores group
//     totals to LDS; wave0 alone does a 512-elem global warm-up.
//     One barrier. Phase2: each wave chains S exactly over prior waves'
//     totals (3 fmafs), then emits outputs. No wave serialization (R7's
//     mistake); warm traffic 32->8MB, total 160->136MB; interior chunks
//     now EXACT (error only at block-boundary warm truncation, same 512
//     window as before). Predict 31-35us profiled.

#define DT_F  0.1f
#define S_LEN 65536
#define B_ROWS 256
#define CHUNK 1024
#define WARM  512
#define WPB   4                      // waves per block = consecutive chunks
#define CPR   (S_LEN / CHUNK)        // 64 chunks per row
#define BPR   (CPR / WPB)            // 16 blocks per row

typedef float nfloat4 __attribute__((ext_vector_type(4)));

template<int CTRL, int RM>
__device__ __forceinline__ float dpp0(float x) {
    // DPP with old=0: lanes with no valid source (or masked rows) get 0.
    return __int_as_float(__builtin_amdgcn_update_dpp(
        0, __float_as_int(x), CTRL, RM, 0xF, false));
}
template<int N>
__device__ __forceinline__ float dpp_shr(float x) { return dpp0<0x110 + N, 0xF>(x); }
__device__ __forceinline__ float bcast15(float x) { return dpp0<0x142, 0xA>(x); } // lane15->row1, lane47->row3
__device__ __forceinline__ float bcast31(float x) { return dpp0<0x143, 0xC>(x); } // lane31->rows2,3
__device__ __forceinline__ float wshr1(float x)   { return dpp0<0x138, 0xF>(x); } // whole-wave shift, lane0->0
__device__ __forceinline__ float rdl(float x, int l) {
    return __int_as_float(__builtin_amdgcn_readlane(__float_as_int(x), l));
}

__global__ __launch_bounds__(256) void maxwell_scan(
    const float* __restrict__ strain,
    const float* __restrict__ rate,
    const float* __restrict__ log_E,
    const float* __restrict__ log_eta,
    float* __restrict__ out)
{
    __shared__ float Tlds[WPB * 4];   // per-wave group totals
    __shared__ float S0lds;           // wave0's incoming state (warm or 0)

    const int lane = threadIdx.x & 63;
    const int wv   = threadIdx.x >> 6;            // 0..3
    const int row  = blockIdx.x / BPR;
    const int cb   = (blockIdx.x % BPR) * WPB;    // block's first chunk in row
    const int c    = cb + wv;                     // this wave's chunk

    const float E   = __expf(log_E[0]);
    const float eta = __expf(log_eta[0]);
    const float lam = -DT_F * E / eta;            // ln(a)
    const float a   = __expf(lam);
    const float a2 = a * a, a3 = a2 * a, a4 = a2 * a2, a8 = a4 * a4;
    const float a16 = a8 * a8, a32 = a16 * a16, a64 = a32 * a32;
    const float a128 = a64 * a64, a256 = a128 * a128;
    const float a512 = a256 * a256, a768 = a512 * a256, a1024 = a512 * a512;
    const float cc = E * (a - 1.0f);
    const float cca1 = cc * a, cca2 = cc * a2, cca3 = cc * a3;

    const int  lrow = lane & 15;
    const float alane = __expf(lam * (float)(4 * lane));   // a^(4*lane)
    const float wX    = __expf(lam * (float)(4 * lrow));   // a^(4*lrow)
    const float wm1   = wX * a4;                           // a^(4*(lrow+1))
    const float wm2   = (lane >= 48) ? wm1 * a64 : wm1;    // row3 jumps rows 0-1

    const int rowbase = row * S_LEN;
    const int t0 = c * CHUNK;
    const nfloat4* s4 = (const nfloat4*)(strain + rowbase);
    nfloat4*       o4 = (nfloat4*)(out + rowbase);

    // ---- loads: wave0's warm-up first (consumed first), then payload ----
    nfloat4 w0, w1;
    const bool do_warm = (wv == 0) && (cb != 0);
    if (do_warm) {
        const int vw = ((t0 - WARM) >> 2) + lane;
        w0 = s4[vw]; w1 = s4[vw + 64];
    }
    const int vp = (t0 >> 2) + lane;              // payload group g at vp + 64*g
    nfloat4 p0 = s4[vp +   0], p1 = s4[vp +  64], p2 = s4[vp + 128], p3 = s4[vp + 192];

    float etar0 = 0.0f;
    if (c == 0) etar0 = eta * rate[rowbase];      // only the row-start wave

    // full-wave weighted inclusive scan of lane totals
    auto scanW = [&](float fl3) -> float {
        float D = fl3, v;
        v = dpp_shr<1>(D); D = fmaf(a4,  v, D);
        v = dpp_shr<2>(D); D = fmaf(a8,  v, D);
        v = dpp_shr<4>(D); D = fmaf(a16, v, D);
        v = dpp_shr<8>(D); D = fmaf(a32, v, D);
        v = bcast15(D);    D = fmaf(wm1, v, D);   // rows 1,3 += w*(prev row total)
        v = bcast31(D);    D = fmaf(wm2, v, D);   // rows 2,3 += w*(rows 0-1 prefix)
        return D;
    };
    auto groupW = [&](nfloat4 pf) -> float {
        float fl = pf.x;
        fl = fmaf(a, fl, pf.y); fl = fmaf(a, fl, pf.z); fl = fmaf(a, fl, pf.w);
        return scanW(fl);
    };

    // ---- phase 1: per-group wave scans; publish totals (lane63 of W) ----
    float W0 = groupW(p0), W1 = groupW(p1), W2 = groupW(p2), W3 = groupW(p3);
    if (lane == 63) {
        Tlds[wv * 4 + 0] = W0; Tlds[wv * 4 + 1] = W1;
        Tlds[wv * 4 + 2] = W2; Tlds[wv * 4 + 3] = W3;
    }
    float S0 = 0.0f;
    if (do_warm) {
        float Tw0 = rdl(groupW(w0), 63);
        float Tw1 = rdl(groupW(w1), 63);
        S0 = fmaf(a256, Tw0, Tw1);                // warm scan of 512 elems
    }
    if (threadIdx.x == 0) S0lds = S0;
    __syncthreads();

    // ---- phase 2: exact S chain over prior waves' chunks, then outputs ----
    float S = S0lds;
    for (int j = 0; j < wv; ++j) {                // uniform per wave
        float Tc = Tlds[j * 4 + 0];
        Tc = fmaf(a256, Tc, Tlds[j * 4 + 1]);
        Tc = fmaf(a256, Tc, Tlds[j * 4 + 2]);
        Tc = fmaf(a256, Tc, Tlds[j * 4 + 3]);
        S = fmaf(a1024, S, Tc);
    }
    const float T0 = Tlds[wv * 4 + 0], T1 = Tlds[wv * 4 + 1], T2 = Tlds[wv * 4 + 2];
    const float Sg0 = S;
    const float Sg1 = fmaf(a256, Sg0, T0);
    const float Sg2 = fmaf(a256, Sg1, T1);
    const float Sg3 = fmaf(a256, Sg2, T2);

    const float rl0 = etar0 * alane;              // eta*r0 * a^(4*lane)
    const float rl1 = rl0 * a, rl2 = rl0 * a2, rl3 = rl0 * a3;

    auto outg = [&](nfloat4 pf, float W, float Sg, float bse, int vo) {
        float fl0 = pf.x;
        float fl1 = fmaf(a, fl0, pf.y);
        float fl2 = fmaf(a, fl1, pf.z);
        float X  = wshr1(W);                      // W[lane-1], lane0 -> 0
        float Xs = fmaf(alane, Sg, X);            // + incoming state
        nfloat4 o;
        o.x = fmaf(cc,   Xs, E * pf.x);
        o.y = fmaf(cca1, Xs, fmaf(cc, fl0, E * pf.y));
        o.z = fmaf(cca2, Xs, fmaf(cc, fl1, E * pf.z));
        o.w = fmaf(cca3, Xs, fmaf(cc, fl2, E * pf.w));
        o.x = fmaf(bse, rl0, o.x);
        o.y = fmaf(bse, rl1, o.y);
        o.z = fmaf(bse, rl2, o.z);
        o.w = fmaf(bse, rl3, o.w);
        o4[vo] = o;
    };
    outg(p0, W0, Sg0, 1.0f, vp +   0);
    outg(p1, W1, Sg1, a256, vp +  64);
    outg(p2, W2, Sg2, a512, vp + 128);
    outg(p3, W3, Sg3, a768, vp + 192);
}

extern "C" void kernel_launch(void* const* d_in, const int* in_sizes, int n_in,
                              void* d_out, int out_size, void* d_ws, size_t ws_size,
                              hipStream_t stream) {
    const float* strain  = (const float*)d_in[0];
    const float* rate    = (const float*)d_in[1];
    const float* log_E   = (const float*)d_in[2];
    const float* log_eta = (const float*)d_in[3];
    float* out = (float*)d_out;

    const int blocks = B_ROWS * BPR;              // 4096 blocks, 16384 waves
    maxwell_scan<<<blocks, 256, 0, stream>>>(strain, rate, log_E, log_eta, out);
}